// Round 4
// baseline (1431.053 us; speedup 1.0000x reference)
//
#include <hip/hip_runtime.h>
#include <math.h>

// ---------------------------------------------------------------------------
// LinearNO block, MI355X/gfx950. DTYPE-ADAPTIVE: on-device sniffer decides
// whether d_in/d_out are fp32 (reference dtype) or bf16 (dataset variant).
// Interior pipeline is bf16 MFMA either way; only input loads / final stores
// branch (wave-uniform flag).
//
// B=8 N=8192 C=256 H=8 D=32 S=32 HID=1024. 65536 token rows of 256.
//
// Memory plan (ws = 23.6 MB only):
//   d_out bytes [0, 33.5MB) as bf16 scratch (safe under both dtypes):
//     xmid (Wx gemm out) -> qkv2d (q_qkv in-place) -> h (Wo gemm in-place,
//     BN=256 so each block reads only its own rows) -> final out (MLP chunks
//     processed DESCENDING so fp32 out writes only clobber dead h rows;
//     chunk 0 residual pre-copied to ws).
//   ws: hid chunk (16MB) | bf16 weight table (1.3MB) | h0res copy (4MB) |
//       fp32: mu1,rs1,mu2,rs2,kvg,zg,wqf,wkf,wvf,flag (~1.4MB)
// ---------------------------------------------------------------------------

typedef __attribute__((ext_vector_type(8))) short bf8;
typedef __attribute__((ext_vector_type(4))) float f32x4;
typedef __attribute__((ext_vector_type(4))) unsigned short u16x4;
typedef __attribute__((ext_vector_type(8))) unsigned short u16x8;

__device__ __forceinline__ float b2f(unsigned short x) {
  union { unsigned u; float f; } t; t.u = ((unsigned)x) << 16; return t.f;
}
__device__ __forceinline__ unsigned short f2b(float f) {
  union { float f; unsigned u; } t; t.f = f;
  unsigned r = t.u + 0x7fffu + ((t.u >> 16) & 1u);
  return (unsigned short)(r >> 16);
}
__device__ __forceinline__ float gelu_exact(float x) {
  return 0.5f * x * (1.0f + erff(x * 0.7071067811865475f));
}

// ---------------------------------------------------------------------------
// Dtype sniffer: bf16-packed N(0,1) data has bits 14:7 of each u16 (the bf16
// exponent) in [117,130] w.p. ~0.998; fp32 mantissa bits land there w.p. ~5%.
// ---------------------------------------------------------------------------
__global__ void sniff_kernel(const unsigned* __restrict__ fx, int* __restrict__ flag) {
  if (threadIdx.x == 0) {
    int cnt = 0;
    for (int i = 0; i < 64; i++) {
      unsigned e = (fx[i] >> 7) & 0xFFu;
      cnt += (e >= 117u && e <= 130u) ? 1 : 0;
    }
    *flag = (cnt >= 32) ? 1 : 0;   // 1 = inputs are bf16, 0 = fp32
  }
}

// ---------------------------------------------------------------------------
// Convert all weights/biases to a bf16 table (branch on flag).
// ---------------------------------------------------------------------------
struct CvtDesc { const void* src[15]; int off[15]; int n[15]; };

__global__ __launch_bounds__(256) void cvt_tab(CvtDesc d, unsigned short* __restrict__ wtab,
                                               const int* __restrict__ flagp) {
  const int seg = blockIdx.y;
  const int i = blockIdx.x * 256 + threadIdx.x;
  if (i >= d.n[seg]) return;
  unsigned short o;
  if (*flagp) o = ((const unsigned short*)d.src[seg])[i];
  else        o = f2b(((const float*)d.src[seg])[i]);
  wtab[d.off[seg] + i] = o;
}

// Exact fp32 copies of Wq/Wk/Wv (used in VALU math — keep full precision).
struct CvtfDesc { const void* src[3]; };
__global__ __launch_bounds__(256) void cvt_f(CvtfDesc d, float* __restrict__ outp,
                                             const int* __restrict__ flagp) {
  const int seg = blockIdx.y;                 // 3 segs, n=1024 each
  const int i = blockIdx.x * 256 + threadIdx.x;   // grid.x = 4
  float v;
  if (*flagp) v = b2f(((const unsigned short*)d.src[seg])[i]);
  else        v = ((const float*)d.src[seg])[i];
  outp[seg * 1024 + i] = v;
}

// ---------------------------------------------------------------------------
// LN stats (mu, rstd) per row of 256. amode=1: branch input dtype on flag;
// amode=0: input is bf16 (interior tensor). One wave/row, 4 rows/block.
// ---------------------------------------------------------------------------
__global__ __launch_bounds__(256) void ln_stats(
    const void* __restrict__ X, const int* __restrict__ flagp, int amode,
    float* __restrict__ MU, float* __restrict__ RS)
{
  const int lane = threadIdx.x & 63;
  const int wave = threadIdx.x >> 6;
  const size_t row = (size_t)blockIdx.x * 4 + wave;
  const size_t base = row * 256 + lane * 4;
  const bool abf = amode ? ((*flagp) != 0) : true;
  float x0, x1, x2, x3;
  if (abf) {
    u16x4 uv = *(const u16x4*)&((const unsigned short*)X)[base];
    x0 = b2f(uv[0]); x1 = b2f(uv[1]); x2 = b2f(uv[2]); x3 = b2f(uv[3]);
  } else {
    f32x4 t = *(const f32x4*)&((const float*)X)[base];
    x0 = t[0]; x1 = t[1]; x2 = t[2]; x3 = t[3];
  }
  float s = x0 + x1 + x2 + x3;
  float q = x0*x0 + x1*x1 + x2*x2 + x3*x3;
  #pragma unroll
  for (int m = 1; m < 64; m <<= 1) { s += __shfl_xor(s, m, 64); q += __shfl_xor(q, m, 64); }
  float mean = s * (1.0f / 256.0f);
  float var  = q * (1.0f / 256.0f) - mean * mean;
  if (lane == 0) { MU[row] = mean; RS[row] = rsqrtf(var + 1e-5f); }
}

// ---------------------------------------------------------------------------
// MFMA GEMM with LN applied to A during staging:
//   a[row,k] = (A[row,k]-mu[row])*rs[row]*lw[k]+lb[k];  Y = a @ W^T + bias
// act=1 -> exact GELU. amode: A dtype branch (1=use flag, 0=bf16).
// 128x128 tile, 4 waves 2x2, 4x4 of 16x16x32 MFMA, BKP=48 pad.
// ---------------------------------------------------------------------------
#define BM 128
#define BN 128
#define BK 32
#define BKP 48

__global__ __launch_bounds__(256) void gemm_bt_ln(
    const void* __restrict__ A, const int* __restrict__ flagp, int amode,
    const float* __restrict__ MU, const float* __restrict__ RS,
    const unsigned short* __restrict__ lw, const unsigned short* __restrict__ lb,
    const unsigned short* __restrict__ W, const unsigned short* __restrict__ bias,
    unsigned short* __restrict__ Y, int M, int N, int K, int act)
{
  __shared__ __align__(16) unsigned short lA[BM * BKP];
  __shared__ __align__(16) unsigned short lB[BN * BKP];
  const int tid = threadIdx.x, lane = tid & 63, wave = tid >> 6;
  const int bm = blockIdx.x * BM, bn = blockIdx.y * BN;
  const int wm = (wave >> 1) * 64, wn = (wave & 1) * 64;
  const int quad = lane >> 4, l16 = lane & 15;
  const bool abf = amode ? ((*flagp) != 0) : true;
  const unsigned short* Ab = (const unsigned short*)A;
  const float* Af = (const float*)A;

  f32x4 acc[4][4] = {};
  const int r0 = tid >> 2;
  const int co = (tid & 3) * 8;

  for (int k0 = 0; k0 < K; k0 += BK) {
    u16x8 wv8 = *(const u16x8*)&lw[k0 + co];
    u16x8 bv8 = *(const u16x8*)&lb[k0 + co];
    __syncthreads();
    #pragma unroll
    for (int half = 0; half < 2; half++) {
      const int ar = bm + r0 + half * 64;
      const float m_ = MU[ar], r_ = RS[ar];
      float xv[8];
      if (abf) {
        u16x8 t = *(const u16x8*)&Ab[(size_t)ar * K + k0 + co];
        #pragma unroll
        for (int e = 0; e < 8; e++) xv[e] = b2f(t[e]);
      } else {
        f32x4 t0 = *(const f32x4*)&Af[(size_t)ar * K + k0 + co];
        f32x4 t1 = *(const f32x4*)&Af[(size_t)ar * K + k0 + co + 4];
        xv[0]=t0[0]; xv[1]=t0[1]; xv[2]=t0[2]; xv[3]=t0[3];
        xv[4]=t1[0]; xv[5]=t1[1]; xv[6]=t1[2]; xv[7]=t1[3];
      }
      u16x8 o;
      #pragma unroll
      for (int e = 0; e < 8; e++)
        o[e] = f2b((xv[e] - m_) * r_ * b2f(wv8[e]) + b2f(bv8[e]));
      *(u16x8*)&lA[(r0 + half * 64) * BKP + co] = o;
    }
    *(u16x8*)&lB[r0 * BKP + co]        = *(const u16x8*)&W[(size_t)(bn + r0) * K + k0 + co];
    *(u16x8*)&lB[(r0 + 64) * BKP + co] = *(const u16x8*)&W[(size_t)(bn + r0 + 64) * K + k0 + co];
    __syncthreads();

    bf8 af[4], bfr[4];
    #pragma unroll
    for (int i = 0; i < 4; i++) af[i]  = *(const bf8*)&lA[(wm + i * 16 + l16) * BKP + quad * 8];
    #pragma unroll
    for (int j = 0; j < 4; j++) bfr[j] = *(const bf8*)&lB[(wn + j * 16 + l16) * BKP + quad * 8];
    #pragma unroll
    for (int i = 0; i < 4; i++)
      #pragma unroll
      for (int j = 0; j < 4; j++)
        acc[i][j] = __builtin_amdgcn_mfma_f32_16x16x32_bf16(af[i], bfr[j], acc[i][j], 0, 0, 0);
  }

  // C/D layout: col = lane&15, row = quad*4 + reg  [m89/m91 verified]
  #pragma unroll
  for (int i = 0; i < 4; i++) {
    #pragma unroll
    for (int j = 0; j < 4; j++) {
      const int col  = bn + wn + j * 16 + l16;
      const int rowb = bm + wm + i * 16 + quad * 4;
      const float bv = b2f(bias[col]);
      #pragma unroll
      for (int r = 0; r < 4; r++) {
        float v = acc[i][j][r] + bv;
        if (act) v = gelu_exact(v);
        Y[(size_t)(rowb + r) * N + col] = f2b(v);
      }
    }
  }
}

// ---------------------------------------------------------------------------
// Wo GEMM, IN-PLACE over d_out: h = qkv2d @ Wo^T + bo + fx.  BN = 256 = N so
// each block reads ONLY the 128 rows it writes (no cross-block read/write
// race). 4 waves side by side (wn = wave*64), each 128x64 = 8x4 MFMA tiles.
// fx residual branches on dtype.
// ---------------------------------------------------------------------------
__global__ __launch_bounds__(256) void gemm_wo(
    const unsigned short* __restrict__ A,     // qkv2d [65536,256] (in d_out)
    const unsigned short* __restrict__ W,     // Wo bf16 [256,256]
    const unsigned short* __restrict__ bias,  // bo
    const void* __restrict__ Res,             // fx (raw dtype)
    const int* __restrict__ flagp,
    unsigned short* __restrict__ Y)           // == A region (in-place)
{
  __shared__ __align__(16) unsigned short lA[128 * BKP];  // 12 KB
  __shared__ __align__(16) unsigned short lB[256 * BKP];  // 24 KB
  const int tid = threadIdx.x, lane = tid & 63, wave = tid >> 6;
  const int bm = blockIdx.x * 128;
  const int wn = wave * 64;
  const int quad = lane >> 4, l16 = lane & 15;
  const int K = 256;
  const bool rbf = (*flagp) != 0;

  f32x4 acc[8][4] = {};
  const int r0 = tid >> 2;
  const int co = (tid & 3) * 8;

  for (int k0 = 0; k0 < 256; k0 += BK) {
    __syncthreads();
    *(u16x8*)&lA[r0 * BKP + co]        = *(const u16x8*)&A[(size_t)(bm + r0) * K + k0 + co];
    *(u16x8*)&lA[(r0 + 64) * BKP + co] = *(const u16x8*)&A[(size_t)(bm + r0 + 64) * K + k0 + co];
    #pragma unroll
    for (int q4 = 0; q4 < 4; q4++)
      *(u16x8*)&lB[(r0 + q4 * 64) * BKP + co] = *(const u16x8*)&W[(size_t)(r0 + q4 * 64) * K + k0 + co];
    __syncthreads();

    bf8 af[8], bfr[4];
    #pragma unroll
    for (int i = 0; i < 8; i++) af[i]  = *(const bf8*)&lA[(i * 16 + l16) * BKP + quad * 8];
    #pragma unroll
    for (int j = 0; j < 4; j++) bfr[j] = *(const bf8*)&lB[(wn + j * 16 + l16) * BKP + quad * 8];
    #pragma unroll
    for (int i = 0; i < 8; i++)
      #pragma unroll
      for (int j = 0; j < 4; j++)
        acc[i][j] = __builtin_amdgcn_mfma_f32_16x16x32_bf16(af[i], bfr[j], acc[i][j], 0, 0, 0);
  }

  #pragma unroll
  for (int i = 0; i < 8; i++) {
    #pragma unroll
    for (int j = 0; j < 4; j++) {
      const int col  = wn + j * 16 + l16;
      const int rowb = bm + i * 16 + quad * 4;
      const float bv = b2f(bias[col]);
      #pragma unroll
      for (int r = 0; r < 4; r++) {
        const size_t idx = (size_t)(rowb + r) * 256 + col;
        float v = acc[i][j][r] + bv;
        v += rbf ? b2f(((const unsigned short*)Res)[idx]) : ((const float*)Res)[idx];
        Y[idx] = f2b(v);
      }
    }
  }
}

// ---------------------------------------------------------------------------
// W2 GEMM + h residual + dtype-branched final store to d_out.
// ---------------------------------------------------------------------------
__global__ __launch_bounds__(256) void gemm_w2out(
    const unsigned short* __restrict__ A,     // hid [8192,1024]
    const unsigned short* __restrict__ W,     // W2 bf16 [256,1024]
    const unsigned short* __restrict__ bias,  // b2
    const unsigned short* __restrict__ Res,   // h rows (local) or h0res copy
    void* __restrict__ OUT, const int* __restrict__ flagp, long out_row0)
{
  __shared__ __align__(16) unsigned short lA[BM * BKP];
  __shared__ __align__(16) unsigned short lB[BN * BKP];
  const int tid = threadIdx.x, lane = tid & 63, wave = tid >> 6;
  const int bm = blockIdx.x * BM, bn = blockIdx.y * BN;
  const int wm = (wave >> 1) * 64, wn = (wave & 1) * 64;
  const int quad = lane >> 4, l16 = lane & 15;
  const int K = 1024, N = 256;
  const bool obf = (*flagp) != 0;

  f32x4 acc[4][4] = {};
  const int r0 = tid >> 2;
  const int co = (tid & 3) * 8;

  for (int k0 = 0; k0 < 1024; k0 += BK) {
    __syncthreads();
    *(u16x8*)&lA[r0 * BKP + co]        = *(const u16x8*)&A[(size_t)(bm + r0) * K + k0 + co];
    *(u16x8*)&lB[r0 * BKP + co]        = *(const u16x8*)&W[(size_t)(bn + r0) * K + k0 + co];
    *(u16x8*)&lA[(r0 + 64) * BKP + co] = *(const u16x8*)&A[(size_t)(bm + r0 + 64) * K + k0 + co];
    *(u16x8*)&lB[(r0 + 64) * BKP + co] = *(const u16x8*)&W[(size_t)(bn + r0 + 64) * K + k0 + co];
    __syncthreads();

    bf8 af[4], bfr[4];
    #pragma unroll
    for (int i = 0; i < 4; i++) af[i]  = *(const bf8*)&lA[(wm + i * 16 + l16) * BKP + quad * 8];
    #pragma unroll
    for (int j = 0; j < 4; j++) bfr[j] = *(const bf8*)&lB[(wn + j * 16 + l16) * BKP + quad * 8];
    #pragma unroll
    for (int i = 0; i < 4; i++)
      #pragma unroll
      for (int j = 0; j < 4; j++)
        acc[i][j] = __builtin_amdgcn_mfma_f32_16x16x32_bf16(af[i], bfr[j], acc[i][j], 0, 0, 0);
  }

  #pragma unroll
  for (int i = 0; i < 4; i++) {
    #pragma unroll
    for (int j = 0; j < 4; j++) {
      const int col  = bn + wn + j * 16 + l16;
      const int rowb = bm + wm + i * 16 + quad * 4;
      const float bv = b2f(bias[col]);
      #pragma unroll
      for (int r = 0; r < 4; r++) {
        const int row = rowb + r;
        float v = acc[i][j][r] + bv + b2f(Res[(size_t)row * N + col]);
        const size_t oidx = (size_t)(out_row0 + row) * N + col;
        if (obf) ((unsigned short*)OUT)[oidx] = f2b(v);
        else     ((float*)OUT)[oidx] = v;
      }
    }
  }
}

// ---------------------------------------------------------------------------
// headproj_kv: per 64-token block: e^kl (fp16 LDS), v (fp16 LDS); per-(h,s)
// thread accumulates kv += e*v, z += e -> global fp32 atomics (all-positive;
// order noise << 2% threshold). Wk/Wv in exact fp32.
// ---------------------------------------------------------------------------
__global__ __launch_bounds__(256) void headproj_kv(
    const unsigned short* __restrict__ Xmid,
    const float* __restrict__ Wkf, const float* __restrict__ Wvf,
    float* __restrict__ kvg, float* __restrict__ zg)
{
  __shared__ __align__(16) unsigned short xs[64 * 256];   // 32 KB
  __shared__ float wk[1024], wv[1024];                    // 8 KB
  __shared__ _Float16 ev[64 * 256];                       // 32 KB
  __shared__ _Float16 vv[64 * 256];                       // 32 KB
  const int tid = threadIdx.x;
  const size_t t0 = (size_t)blockIdx.x * 64;
  const int b = (int)(t0 >> 13);

  #pragma unroll
  for (int i = 0; i < 16; i++) {
    int flat = i * 1024 + tid * 4;
    *(u16x4*)&xs[flat] = *(const u16x4*)&Xmid[t0 * 256 + flat];
  }
  for (int i = tid; i < 1024; i += 256) { wk[i] = Wkf[i]; wv[i] = Wvf[i]; }
  __syncthreads();

  #pragma unroll
  for (int p = 0; p < 2; p++) {
    const int idx = p * 256 + tid;
    const int tk = idx >> 3, h = idx & 7;
    float xr[32];
    #pragma unroll
    for (int d = 0; d < 32; d++) xr[d] = b2f(xs[tk * 256 + h * 32 + d]);
    for (int s = 0; s < 32; s++) {
      float a = 0.f;
      #pragma unroll
      for (int d = 0; d < 32; d++) a += xr[d] * wk[s * 32 + d];
      ev[tk * 256 + h * 32 + s] = (_Float16)__expf(a);
    }
    for (int d2 = 0; d2 < 32; d2++) {
      float a = 0.f;
      #pragma unroll
      for (int d = 0; d < 32; d++) a += xr[d] * wv[d2 * 32 + d];
      vv[tk * 256 + h * 32 + d2] = (_Float16)a;
    }
  }
  __syncthreads();

  const int h2 = tid >> 5, s2 = tid & 31;
  float acc[32]; float zacc = 0.f;
  #pragma unroll
  for (int d = 0; d < 32; d++) acc[d] = 0.f;
  for (int t = 0; t < 64; t++) {
    const float e = (float)ev[t * 256 + h2 * 32 + s2];
    zacc += e;
    const int vb = t * 256 + h2 * 32;
    #pragma unroll
    for (int d = 0; d < 32; d++) acc[d] += e * (float)vv[vb + d];
  }
  float* kp = &kvg[(((size_t)(b * 8 + h2)) * 32 + s2) * 32];
  #pragma unroll
  for (int d = 0; d < 32; d++) atomicAdd(&kp[d], acc[d]);
  atomicAdd(&zg[(b * 8 + h2) * 32 + s2], zacc);
}

__global__ __launch_bounds__(256) void zero_f32(float* __restrict__ p, int n) {
  int i = blockIdx.x * 256 + threadIdx.x;
  if (i < n) p[i] = 0.f;
}

__global__ __launch_bounds__(256) void kv_norm(float* __restrict__ kvg,
                                               const float* __restrict__ zg) {
  int i = blockIdx.x * 256 + threadIdx.x;   // 65536
  kvg[i] = kvg[i] / zg[i >> 5];
}

// ---------------------------------------------------------------------------
// q_qkv IN-PLACE on d_out: reads its 64 xmid rows fully into LDS, then writes
// qkv rows to the same addresses. q = softmax(x_h @ Wq^T) in fp32 regs.
// ---------------------------------------------------------------------------
__global__ __launch_bounds__(256) void q_qkv(
    const unsigned short* __restrict__ Xmid,
    const float* __restrict__ Wqf,
    const float* __restrict__ kvg,
    unsigned short* __restrict__ Y)     // == Xmid (in-place)
{
  __shared__ __align__(16) unsigned short xs[64 * 256];   // 32 KB
  __shared__ float wq[1024];                              // 4 KB
  __shared__ float kvn[8192];                             // 32 KB
  const int tid = threadIdx.x;
  const size_t t0 = (size_t)blockIdx.x * 64;
  const int b = (int)(t0 >> 13);

  #pragma unroll
  for (int i = 0; i < 16; i++) {
    int flat = i * 1024 + tid * 4;
    *(u16x4*)&xs[flat] = *(const u16x4*)&Xmid[t0 * 256 + flat];
  }
  for (int i = tid; i < 1024; i += 256) wq[i] = Wqf[i];
  for (int i = tid; i < 8192; i += 256) kvn[i] = kvg[(size_t)b * 8192 + i];
  __syncthreads();

  #pragma unroll
  for (int p = 0; p < 2; p++) {
    const int idx = p * 256 + tid;
    const int tk = idx >> 3, h = idx & 7;
    float xr[32];
    #pragma unroll
    for (int d = 0; d < 32; d++) xr[d] = b2f(xs[tk * 256 + h * 32 + d]);
    float ql[32]; float mx = -1e30f;
    for (int s = 0; s < 32; s++) {
      float a = 0.f;
      #pragma unroll
      for (int d = 0; d < 32; d++) a += xr[d] * wq[s * 32 + d];
      ql[s] = a; mx = fmaxf(mx, a);
    }
    float z = 0.f;
    for (int s = 0; s < 32; s++) { float e = __expf(ql[s] - mx); ql[s] = e; z += e; }
    const float rz = 1.0f / z;
    float acc[32];
    #pragma unroll
    for (int d = 0; d < 32; d++) acc[d] = 0.f;
    for (int s = 0; s < 32; s++) {
      const float qs = ql[s];
      const float* kp = &kvn[h * 1024 + s * 32];
      #pragma unroll
      for (int d = 0; d < 32; d++) acc[d] += qs * kp[d];
    }
    const size_t base = (t0 + tk) * 256 + h * 32;
    for (int d4 = 0; d4 < 32; d4 += 4) {
      u16x4 o;
      o[0] = f2b(acc[d4 + 0] * rz); o[1] = f2b(acc[d4 + 1] * rz);
      o[2] = f2b(acc[d4 + 2] * rz); o[3] = f2b(acc[d4 + 3] * rz);
      *(u16x4*)&Y[base + d4] = o;
    }
  }
}

__global__ __launch_bounds__(256) void copy_h0(const unsigned short* __restrict__ src,
                                               unsigned short* __restrict__ dst) {
  size_t i = ((size_t)blockIdx.x * 256 + threadIdx.x) * 8;   // grid 1024 -> 2,097,152
  *(u16x8*)&dst[i] = *(const u16x8*)&src[i];
}

// ---------------------------------------------------------------------------
extern "C" void kernel_launch(void* const* d_in, const int* in_sizes, int n_in,
                              void* d_out, int out_size, void* d_ws, size_t ws_size,
                              hipStream_t stream)
{
  const void* fx   = d_in[0];
  const void* ln1w = d_in[1];
  const void* ln1b = d_in[2];
  const void* Wx   = d_in[3];
  const void* bx   = d_in[4];
  const void* Wq   = d_in[5];
  const void* Wk   = d_in[6];
  const void* Wv   = d_in[7];
  const void* Wo   = d_in[8];
  const void* bo   = d_in[9];
  const void* ln2w = d_in[10];
  const void* ln2b = d_in[11];
  const void* W1   = d_in[12];
  const void* b1   = d_in[13];
  const void* W2   = d_in[14];
  const void* b2   = d_in[15];

  // ws layout (23.6 MB)
  unsigned short* ws    = (unsigned short*)d_ws;
  unsigned short* hid   = ws;                    // 8,388,608 u16 (16 MB)
  unsigned short* wtab  = ws + 8388608;          // 661,248 u16
  unsigned short* h0res = wtab + 661248;         // 2,097,152 u16
  float* fp  = (float*)(h0res + 2097152);
  float* mu1 = fp;                // 65536
  float* rs1 = fp + 65536;
  float* mu2 = fp + 131072;
  float* rs2 = fp + 196608;
  float* kvg = fp + 262144;       // 65536
  float* zg  = fp + 327680;       // 2048
  float* wqf = fp + 329728;       // 1024
  float* wkf = fp + 330752;       // 1024
  float* wvf = fp + 331776;       // 1024
  int* flagp = (int*)(fp + 332800);

  // bf16 weight-table offsets
  const int OFF_LN1W=0, OFF_LN1B=256, OFF_WX=512, OFF_BX=66048,
            OFF_WO=69376, OFF_BO=134912, OFF_LN2W=135168, OFF_LN2B=135424,
            OFF_W1=135680, OFF_B1=397824, OFF_W2=398848, OFF_B2=660992;

  unsigned short* xm = (unsigned short*)d_out;   // xmid->qkv2d->h (bf16 scratch)

  // 0. dtype sniff
  sniff_kernel<<<1, 64, 0, stream>>>((const unsigned*)fx, flagp);

  // 1. weight conversion
  CvtDesc cd;
  const void* srcs[15] = {ln1w, ln1b, Wx, bx, Wq, Wk, Wv, Wo, bo, ln2w, ln2b, W1, b1, W2, b2};
  const int offs[15]   = {OFF_LN1W, OFF_LN1B, OFF_WX, OFF_BX, 66304, 67328, 68352,
                          OFF_WO, OFF_BO, OFF_LN2W, OFF_LN2B, OFF_W1, OFF_B1, OFF_W2, OFF_B2};
  const int ns[15]     = {256, 256, 65536, 256, 1024, 1024, 1024, 65536, 256, 256, 256,
                          262144, 1024, 262144, 256};
  for (int i = 0; i < 15; i++) { cd.src[i] = srcs[i]; cd.off[i] = offs[i]; cd.n[i] = ns[i]; }
  cvt_tab<<<dim3(1024, 15), 256, 0, stream>>>(cd, wtab, flagp);
  CvtfDesc cf; cf.src[0] = Wq; cf.src[1] = Wk; cf.src[2] = Wv;
  cvt_f<<<dim3(4, 3), 256, 0, stream>>>(cf, wqf, flagp);

  // 2. LN1 stats; xmid = LN1(fx) @ Wx^T + bx  -> d_out
  ln_stats<<<16384, 256, 0, stream>>>(fx, flagp, 1, mu1, rs1);
  gemm_bt_ln<<<dim3(512, 2), 256, 0, stream>>>(fx, flagp, 1, mu1, rs1,
      wtab + OFF_LN1W, wtab + OFF_LN1B, wtab + OFF_WX, wtab + OFF_BX,
      xm, 65536, 256, 256, 0);

  // 3. kv accumulation + normalize
  zero_f32<<<264, 256, 0, stream>>>(kvg, 67584);
  headproj_kv<<<1024, 256, 0, stream>>>(xm, wkf, wvf, kvg, zg);
  kv_norm<<<256, 256, 0, stream>>>(kvg, zg);

  // 4. qkv2d = softmax_q . kv   (in-place over xmid)
  q_qkv<<<1024, 256, 0, stream>>>(xm, wqf, kvg, xm);

  // 5. h = qkv2d @ Wo^T + bo + fx   (in-place, BN=256)
  gemm_wo<<<512, 256, 0, stream>>>(xm, wtab + OFF_WO, wtab + OFF_BO, fx, flagp, xm);

  // 6. LN2 stats; protect chunk-0 residual
  ln_stats<<<16384, 256, 0, stream>>>(xm, flagp, 0, mu2, rs2);
  copy_h0<<<1024, 256, 0, stream>>>(xm, h0res);

  // 7. MLP, 8 chunks of 8192 rows, DESCENDING (fp32 out writes only clobber
  //    already-consumed h rows; chunk 0 uses the h0res copy).
  for (int c = 7; c >= 0; c--) {
    unsigned short* hrows = xm + (size_t)c * 8192 * 256;
    gemm_bt_ln<<<dim3(64, 8), 256, 0, stream>>>(hrows, flagp, 0,
        mu2 + c * 8192, rs2 + c * 8192, wtab + OFF_LN2W, wtab + OFF_LN2B,
        wtab + OFF_W1, wtab + OFF_B1, hid, 8192, 1024, 256, 1);
    gemm_w2out<<<dim3(64, 2), 256, 0, stream>>>(hid, wtab + OFF_W2, wtab + OFF_B2,
        (c == 0 ? h0res : hrows), d_out, flagp, (long)c * 8192);
  }
}

// Round 6
// 843.390 us; speedup vs baseline: 1.6968x; 1.6968x over previous
//
#include <hip/hip_runtime.h>
#include <math.h>

// ---------------------------------------------------------------------------
// LinearNO block, MI355X/gfx950. Inputs fp32 (sniffed; bf16 fallback).
// Interior pipeline bf16 MFMA. B=8 N=8192 C=256 H=8 D=32 S=32.
//
// Head math via block-diagonal MFMA GEMMs:
//   E2d  = exp(xmid @ Wk_big^T)            [65536,256] bf16 (d_out upper)
//   G    = per-batch E^T X partials        (accumG 256 blocks + reduceG)
//   kv   = (G @ Wv^T) / z                  -> block-diag KVB[b] [256,256]
//   QL   = xmid @ Wq_big^T                 (overwrites E2d slot)
//   Qs   = segment-softmax(QL) in-place
//   qkv  = Qs @ KVB[b]^T (z-batched GEMM)  (overwrites xmid slot)
// Then h = qkv@Wo^T+bo+fx in-place; MLP descending chunks (round-4 proven).
//
// R5 bug fixed here: reduceG extent was 64x8448 (b ran 0..63, read Gp blocks
// up to 2047 of 256 -> garbage -> NaN) and kv_build ran 64 blocks with b
// treated as batch (KVB writes OOB). Now: Gfin = [8][8448], reduceG 67,584
// outputs (grid 264), kv_build grid 8.
// ---------------------------------------------------------------------------

typedef __attribute__((ext_vector_type(8))) short bf8;
typedef __attribute__((ext_vector_type(4))) float f32x4;
typedef __attribute__((ext_vector_type(4))) unsigned short u16x4;
typedef __attribute__((ext_vector_type(8))) unsigned short u16x8;

__device__ __forceinline__ float b2f(unsigned short x) {
  union { unsigned u; float f; } t; t.u = ((unsigned)x) << 16; return t.f;
}
__device__ __forceinline__ unsigned short f2b(float f) {
  union { float f; unsigned u; } t; t.f = f;
  unsigned r = t.u + 0x7fffu + ((t.u >> 16) & 1u);
  return (unsigned short)(r >> 16);
}
__device__ __forceinline__ float gelu_exact(float x) {
  return 0.5f * x * (1.0f + erff(x * 0.7071067811865475f));
}

// --------------------------- dtype sniffer ---------------------------------
__global__ void sniff_kernel(const unsigned* __restrict__ fx, int* __restrict__ flag) {
  if (threadIdx.x == 0) {
    int cnt = 0;
    for (int i = 0; i < 64; i++) {
      unsigned e = (fx[i] >> 7) & 0xFFu;
      cnt += (e >= 117u && e <= 130u) ? 1 : 0;
    }
    *flag = (cnt >= 32) ? 1 : 0;   // 1 = bf16 inputs, 0 = fp32
  }
}

// --------------------------- weight table ----------------------------------
struct CvtDesc { const void* src[15]; int off[15]; int n[15]; };

__global__ __launch_bounds__(256) void cvt_tab(CvtDesc d, unsigned short* __restrict__ wtab,
                                               const int* __restrict__ flagp) {
  const int seg = blockIdx.y;
  const int i = blockIdx.x * 256 + threadIdx.x;
  if (i >= d.n[seg]) return;
  unsigned short o;
  if (*flagp) o = ((const unsigned short*)d.src[seg])[i];
  else        o = f2b(((const float*)d.src[seg])[i]);
  wtab[d.off[seg] + i] = o;
}

// Build block-diagonal Wq_big / Wk_big [256,256]: big[h*32+s][h*32+d]=W[s][d].
__global__ __launch_bounds__(256) void build_big(
    const unsigned short* __restrict__ wq, const unsigned short* __restrict__ wk,
    unsigned short* __restrict__ Wqbig, unsigned short* __restrict__ Wkbig)
{
  const int idx = blockIdx.x * 256 + threadIdx.x;   // grid 256 -> 65536
  const int row = idx >> 8, col = idx & 255;
  const bool same = (row >> 5) == (col >> 5);
  const int wi = (row & 31) * 32 + (col & 31);
  Wqbig[idx] = same ? wq[wi] : (unsigned short)0;
  Wkbig[idx] = same ? wk[wi] : (unsigned short)0;
}

__global__ __launch_bounds__(256) void zero_u16(unsigned short* __restrict__ p, int n) {
  int i8 = (blockIdx.x * 256 + threadIdx.x) * 8;
  if (i8 < n) { u16x8 z = {}; *(u16x8*)&p[i8] = z; }
}

// --------------------------- LN stats --------------------------------------
__global__ __launch_bounds__(256) void ln_stats(
    const void* __restrict__ X, const int* __restrict__ flagp, int amode,
    float* __restrict__ MU, float* __restrict__ RS)
{
  const int lane = threadIdx.x & 63;
  const int wave = threadIdx.x >> 6;
  const size_t row = (size_t)blockIdx.x * 4 + wave;
  const size_t base = row * 256 + lane * 4;
  const bool abf = amode ? ((*flagp) != 0) : true;
  float x0, x1, x2, x3;
  if (abf) {
    u16x4 uv = *(const u16x4*)&((const unsigned short*)X)[base];
    x0 = b2f(uv[0]); x1 = b2f(uv[1]); x2 = b2f(uv[2]); x3 = b2f(uv[3]);
  } else {
    f32x4 t = *(const f32x4*)&((const float*)X)[base];
    x0 = t[0]; x1 = t[1]; x2 = t[2]; x3 = t[3];
  }
  float s = x0 + x1 + x2 + x3;
  float q = x0*x0 + x1*x1 + x2*x2 + x3*x3;
  #pragma unroll
  for (int m = 1; m < 64; m <<= 1) { s += __shfl_xor(s, m, 64); q += __shfl_xor(q, m, 64); }
  float mean = s * (1.0f / 256.0f);
  float var  = q * (1.0f / 256.0f) - mean * mean;
  if (lane == 0) { MU[row] = mean; RS[row] = rsqrtf(var + 1e-5f); }
}

// --------------------------- generic MFMA GEMM -----------------------------
#define BM 128
#define BN 128
#define BK 32
#define BKP 48

// Y[M,N] = A[M,K] @ W[N,K]^T + bias, act: 0 none, 2 exp. z-batched:
// row block = blockIdx.z*mz + ..., W += blockIdx.z*wz.
__global__ __launch_bounds__(256) void gemm_bt(
    const unsigned short* __restrict__ A,
    const unsigned short* __restrict__ W,
    const unsigned short* __restrict__ bias,
    unsigned short* __restrict__ Y,
    int M, int N, int K, int act, int mz, long wz)
{
  __shared__ __align__(16) unsigned short lA[BM * BKP];
  __shared__ __align__(16) unsigned short lB[BN * BKP];
  const int tid = threadIdx.x, lane = tid & 63, wave = tid >> 6;
  const size_t zrow = (size_t)blockIdx.z * mz;
  const int bm = blockIdx.x * BM, bn = blockIdx.y * BN;
  const int wm = (wave >> 1) * 64, wn = (wave & 1) * 64;
  const int quad = lane >> 4, l16 = lane & 15;
  const unsigned short* Wz = W + (size_t)blockIdx.z * wz;

  f32x4 acc[4][4] = {};
  const int r0 = tid >> 2;
  const int co = (tid & 3) * 8;

  for (int k0 = 0; k0 < K; k0 += BK) {
    __syncthreads();
    *(u16x8*)&lA[r0 * BKP + co]        = *(const u16x8*)&A[(zrow + bm + r0) * K + k0 + co];
    *(u16x8*)&lB[r0 * BKP + co]        = *(const u16x8*)&Wz[(size_t)(bn + r0) * K + k0 + co];
    *(u16x8*)&lA[(r0 + 64) * BKP + co] = *(const u16x8*)&A[(zrow + bm + r0 + 64) * K + k0 + co];
    *(u16x8*)&lB[(r0 + 64) * BKP + co] = *(const u16x8*)&Wz[(size_t)(bn + r0 + 64) * K + k0 + co];
    __syncthreads();

    bf8 af[4], bfr[4];
    #pragma unroll
    for (int i = 0; i < 4; i++) af[i]  = *(const bf8*)&lA[(wm + i * 16 + l16) * BKP + quad * 8];
    #pragma unroll
    for (int j = 0; j < 4; j++) bfr[j] = *(const bf8*)&lB[(wn + j * 16 + l16) * BKP + quad * 8];
    #pragma unroll
    for (int i = 0; i < 4; i++)
      #pragma unroll
      for (int j = 0; j < 4; j++)
        acc[i][j] = __builtin_amdgcn_mfma_f32_16x16x32_bf16(af[i], bfr[j], acc[i][j], 0, 0, 0);
  }

  #pragma unroll
  for (int i = 0; i < 4; i++) {
    #pragma unroll
    for (int j = 0; j < 4; j++) {
      const int col  = bn + wn + j * 16 + l16;
      const int rowb = bm + wm + i * 16 + quad * 4;
      const float bv = b2f(bias[col]);
      #pragma unroll
      for (int r = 0; r < 4; r++) {
        float v = acc[i][j][r] + bv;
        if (act == 2) v = __expf(v);
        Y[(zrow + rowb + r) * N + col] = f2b(v);
      }
    }
  }
}

// GEMM with LN applied to A during staging (amode: 1=flag dtype, 0=bf16),
// act=1 -> GELU.
__global__ __launch_bounds__(256) void gemm_bt_ln(
    const void* __restrict__ A, const int* __restrict__ flagp, int amode,
    const float* __restrict__ MU, const float* __restrict__ RS,
    const unsigned short* __restrict__ lw, const unsigned short* __restrict__ lb,
    const unsigned short* __restrict__ W, const unsigned short* __restrict__ bias,
    unsigned short* __restrict__ Y, int M, int N, int K, int act)
{
  __shared__ __align__(16) unsigned short lA[BM * BKP];
  __shared__ __align__(16) unsigned short lB[BN * BKP];
  const int tid = threadIdx.x, lane = tid & 63, wave = tid >> 6;
  const int bm = blockIdx.x * BM, bn = blockIdx.y * BN;
  const int wm = (wave >> 1) * 64, wn = (wave & 1) * 64;
  const int quad = lane >> 4, l16 = lane & 15;
  const bool abf = amode ? ((*flagp) != 0) : true;
  const unsigned short* Ab = (const unsigned short*)A;
  const float* Af = (const float*)A;

  f32x4 acc[4][4] = {};
  const int r0 = tid >> 2;
  const int co = (tid & 3) * 8;

  for (int k0 = 0; k0 < K; k0 += BK) {
    u16x8 wv8 = *(const u16x8*)&lw[k0 + co];
    u16x8 bv8 = *(const u16x8*)&lb[k0 + co];
    __syncthreads();
    #pragma unroll
    for (int half = 0; half < 2; half++) {
      const int ar = bm + r0 + half * 64;
      const float m_ = MU[ar], r_ = RS[ar];
      float xv[8];
      if (abf) {
        u16x8 t = *(const u16x8*)&Ab[(size_t)ar * K + k0 + co];
        #pragma unroll
        for (int e = 0; e < 8; e++) xv[e] = b2f(t[e]);
      } else {
        f32x4 t0 = *(const f32x4*)&Af[(size_t)ar * K + k0 + co];
        f32x4 t1 = *(const f32x4*)&Af[(size_t)ar * K + k0 + co + 4];
        xv[0]=t0[0]; xv[1]=t0[1]; xv[2]=t0[2]; xv[3]=t0[3];
        xv[4]=t1[0]; xv[5]=t1[1]; xv[6]=t1[2]; xv[7]=t1[3];
      }
      u16x8 o;
      #pragma unroll
      for (int e = 0; e < 8; e++)
        o[e] = f2b((xv[e] - m_) * r_ * b2f(wv8[e]) + b2f(bv8[e]));
      *(u16x8*)&lA[(r0 + half * 64) * BKP + co] = o;
    }
    *(u16x8*)&lB[r0 * BKP + co]        = *(const u16x8*)&W[(size_t)(bn + r0) * K + k0 + co];
    *(u16x8*)&lB[(r0 + 64) * BKP + co] = *(const u16x8*)&W[(size_t)(bn + r0 + 64) * K + k0 + co];
    __syncthreads();

    bf8 af[4], bfr[4];
    #pragma unroll
    for (int i = 0; i < 4; i++) af[i]  = *(const bf8*)&lA[(wm + i * 16 + l16) * BKP + quad * 8];
    #pragma unroll
    for (int j = 0; j < 4; j++) bfr[j] = *(const bf8*)&lB[(wn + j * 16 + l16) * BKP + quad * 8];
    #pragma unroll
    for (int i = 0; i < 4; i++)
      #pragma unroll
      for (int j = 0; j < 4; j++)
        acc[i][j] = __builtin_amdgcn_mfma_f32_16x16x32_bf16(af[i], bfr[j], acc[i][j], 0, 0, 0);
  }

  #pragma unroll
  for (int i = 0; i < 4; i++) {
    #pragma unroll
    for (int j = 0; j < 4; j++) {
      const int col  = bn + wn + j * 16 + l16;
      const int rowb = bm + wm + i * 16 + quad * 4;
      const float bv = b2f(bias[col]);
      #pragma unroll
      for (int r = 0; r < 4; r++) {
        float v = acc[i][j][r] + bv;
        if (act) v = gelu_exact(v);
        Y[(size_t)(rowb + r) * N + col] = f2b(v);
      }
    }
  }
}

// Wo GEMM in-place (BN=256 = N, each block reads only the rows it writes).
__global__ __launch_bounds__(256) void gemm_wo(
    const unsigned short* __restrict__ A,
    const unsigned short* __restrict__ W,
    const unsigned short* __restrict__ bias,
    const void* __restrict__ Res, const int* __restrict__ flagp,
    unsigned short* __restrict__ Y)
{
  __shared__ __align__(16) unsigned short lA[128 * BKP];
  __shared__ __align__(16) unsigned short lB[256 * BKP];
  const int tid = threadIdx.x, lane = tid & 63, wave = tid >> 6;
  const int bm = blockIdx.x * 128;
  const int wn = wave * 64;
  const int quad = lane >> 4, l16 = lane & 15;
  const int K = 256;
  const bool rbf = (*flagp) != 0;

  f32x4 acc[8][4] = {};
  const int r0 = tid >> 2;
  const int co = (tid & 3) * 8;

  for (int k0 = 0; k0 < 256; k0 += BK) {
    __syncthreads();
    *(u16x8*)&lA[r0 * BKP + co]        = *(const u16x8*)&A[(size_t)(bm + r0) * K + k0 + co];
    *(u16x8*)&lA[(r0 + 64) * BKP + co] = *(const u16x8*)&A[(size_t)(bm + r0 + 64) * K + k0 + co];
    #pragma unroll
    for (int q4 = 0; q4 < 4; q4++)
      *(u16x8*)&lB[(r0 + q4 * 64) * BKP + co] = *(const u16x8*)&W[(size_t)(r0 + q4 * 64) * K + k0 + co];
    __syncthreads();

    bf8 af[8], bfr[4];
    #pragma unroll
    for (int i = 0; i < 8; i++) af[i]  = *(const bf8*)&lA[(i * 16 + l16) * BKP + quad * 8];
    #pragma unroll
    for (int j = 0; j < 4; j++) bfr[j] = *(const bf8*)&lB[(wn + j * 16 + l16) * BKP + quad * 8];
    #pragma unroll
    for (int i = 0; i < 8; i++)
      #pragma unroll
      for (int j = 0; j < 4; j++)
        acc[i][j] = __builtin_amdgcn_mfma_f32_16x16x32_bf16(af[i], bfr[j], acc[i][j], 0, 0, 0);
  }

  #pragma unroll
  for (int i = 0; i < 8; i++) {
    #pragma unroll
    for (int j = 0; j < 4; j++) {
      const int col  = wn + j * 16 + l16;
      const int rowb = bm + i * 16 + quad * 4;
      const float bv = b2f(bias[col]);
      #pragma unroll
      for (int r = 0; r < 4; r++) {
        const size_t idx = (size_t)(rowb + r) * 256 + col;
        float v = acc[i][j][r] + bv;
        v += rbf ? b2f(((const unsigned short*)Res)[idx]) : ((const float*)Res)[idx];
        Y[idx] = f2b(v);
      }
    }
  }
}

// W2 GEMM + residual + dtype-branched final store.
__global__ __launch_bounds__(256) void gemm_w2out(
    const unsigned short* __restrict__ A,
    const unsigned short* __restrict__ W,
    const unsigned short* __restrict__ bias,
    const unsigned short* __restrict__ Res,
    void* __restrict__ OUT, const int* __restrict__ flagp, long out_row0)
{
  __shared__ __align__(16) unsigned short lA[BM * BKP];
  __shared__ __align__(16) unsigned short lB[BN * BKP];
  const int tid = threadIdx.x, lane = tid & 63, wave = tid >> 6;
  const int bm = blockIdx.x * BM, bn = blockIdx.y * BN;
  const int wm = (wave >> 1) * 64, wn = (wave & 1) * 64;
  const int quad = lane >> 4, l16 = lane & 15;
  const int K = 1024, N = 256;
  const bool obf = (*flagp) != 0;

  f32x4 acc[4][4] = {};
  const int r0 = tid >> 2;
  const int co = (tid & 3) * 8;

  for (int k0 = 0; k0 < 1024; k0 += BK) {
    __syncthreads();
    *(u16x8*)&lA[r0 * BKP + co]        = *(const u16x8*)&A[(size_t)(bm + r0) * K + k0 + co];
    *(u16x8*)&lB[r0 * BKP + co]        = *(const u16x8*)&W[(size_t)(bn + r0) * K + k0 + co];
    *(u16x8*)&lA[(r0 + 64) * BKP + co] = *(const u16x8*)&A[(size_t)(bm + r0 + 64) * K + k0 + co];
    *(u16x8*)&lB[(r0 + 64) * BKP + co] = *(const u16x8*)&W[(size_t)(bn + r0 + 64) * K + k0 + co];
    __syncthreads();

    bf8 af[4], bfr[4];
    #pragma unroll
    for (int i = 0; i < 4; i++) af[i]  = *(const bf8*)&lA[(wm + i * 16 + l16) * BKP + quad * 8];
    #pragma unroll
    for (int j = 0; j < 4; j++) bfr[j] = *(const bf8*)&lB[(wn + j * 16 + l16) * BKP + quad * 8];
    #pragma unroll
    for (int i = 0; i < 4; i++)
      #pragma unroll
      for (int j = 0; j < 4; j++)
        acc[i][j] = __builtin_amdgcn_mfma_f32_16x16x32_bf16(af[i], bfr[j], acc[i][j], 0, 0, 0);
  }

  #pragma unroll
  for (int i = 0; i < 4; i++) {
    #pragma unroll
    for (int j = 0; j < 4; j++) {
      const int col  = bn + wn + j * 16 + l16;
      const int rowb = bm + wm + i * 16 + quad * 4;
      const float bv = b2f(bias[col]);
      #pragma unroll
      for (int r = 0; r < 4; r++) {
        const int row = rowb + r;
        float v = acc[i][j][r] + bv + b2f(Res[(size_t)row * N + col]);
        const size_t oidx = (size_t)(out_row0 + row) * N + col;
        if (obf) ((unsigned short*)OUT)[oidx] = f2b(v);
        else     ((float*)OUT)[oidx] = v;
      }
    }
  }
}

// ---------------------------------------------------------------------------
// accumG: per 256-token block k: partial G[h,s,d] = sum_n E[n,h*32+s]*X[n,h*32+d]
// (+ z partial at [8192+tid]). Batch b owns blocks k = b*32 .. b*32+31.
// ---------------------------------------------------------------------------
__global__ __launch_bounds__(256) void accumG(
    const unsigned short* __restrict__ X,   // xmid [65536,256] bf16
    const unsigned short* __restrict__ E,   // E2d  [65536,256] bf16
    float* __restrict__ Gp)                 // [256][8448]
{
  __shared__ float Xl[64 * 256];                         // 64 KB
  __shared__ __align__(16) unsigned short El[64 * 256];  // 32 KB
  const int tid = threadIdx.x;
  const int k = blockIdx.x;
  const int h = tid >> 5, s = tid & 31;

  float acc[32];
  #pragma unroll
  for (int d = 0; d < 32; d++) acc[d] = 0.f;
  float zacc = 0.f;

  for (int sub = 0; sub < 4; sub++) {
    const size_t r0s = (size_t)k * 256 + sub * 64;
    __syncthreads();
    #pragma unroll
    for (int i = 0; i < 8; i++) {
      const int flat = i * 2048 + tid * 8;     // 16384 elems
      u16x8 xv = *(const u16x8*)&X[r0s * 256 + flat];
      #pragma unroll
      for (int e = 0; e < 8; e++) Xl[flat + e] = b2f(xv[e]);
      *(u16x8*)&El[flat] = *(const u16x8*)&E[r0s * 256 + flat];
    }
    __syncthreads();

    for (int t = 0; t < 64; t++) {
      const float e = b2f(El[t * 256 + h * 32 + s]);
      zacc += e;
      const int xb = t * 256 + h * 32;
      #pragma unroll
      for (int dq = 0; dq < 8; dq++) {
        f32x4 xv = *(const f32x4*)&Xl[xb + dq * 4];
        acc[dq*4+0] += e * xv[0];
        acc[dq*4+1] += e * xv[1];
        acc[dq*4+2] += e * xv[2];
        acc[dq*4+3] += e * xv[3];
      }
    }
  }

  float* gp = &Gp[(size_t)k * 8448 + (size_t)tid * 32];
  #pragma unroll
  for (int dq = 0; dq < 8; dq++) {
    f32x4 o; o[0]=acc[dq*4]; o[1]=acc[dq*4+1]; o[2]=acc[dq*4+2]; o[3]=acc[dq*4+3];
    *(f32x4*)&gp[dq * 4] = o;
  }
  Gp[(size_t)k * 8448 + 8192 + tid] = zacc;
}

// Gfin[b][j] = sum_{i<32} Gp[b*32+i][j], b in 0..7. Total 8*8448 = 67,584.
__global__ __launch_bounds__(256) void reduceG(const float* __restrict__ Gp,
                                               float* __restrict__ Gfin) {
  const int o = blockIdx.x * 256 + threadIdx.x;
  if (o >= 67584) return;
  const int b = o / 8448;
  const int j = o - b * 8448;
  float s = 0.f;
  #pragma unroll 8
  for (int i = 0; i < 32; i++) s += Gp[(size_t)(b * 32 + i) * 8448 + j];
  Gfin[o] = s;
}

// kv_build (8 blocks, one per batch): kv[b,h,s,d] = (sum_dd G*Wv[d,dd]) / z;
// writes block-diag KVB[b][h*32+d][h*32+s] (rest pre-zeroed).
__global__ __launch_bounds__(256) void kv_build(
    const float* __restrict__ Gfin, const unsigned short* __restrict__ Wv,
    unsigned short* __restrict__ KVB)
{
  __shared__ float Gl[8192];    // 32 KB
  __shared__ float zl[256];
  __shared__ float wvt[1024];   // transposed: wvt[dd*32+d] = Wv[d][dd]
  const int tid = threadIdx.x;
  const int b = blockIdx.x;     // batch 0..7
  for (int i = tid; i < 8192; i += 256) Gl[i] = Gfin[(size_t)b * 8448 + i];
  zl[tid] = Gfin[(size_t)b * 8448 + 8192 + tid];
  for (int i = tid; i < 1024; i += 256) {
    const int dd = i >> 5, d = i & 31;
    wvt[i] = b2f(Wv[d * 32 + dd]);
  }
  __syncthreads();

  const int h = tid >> 5, d = tid & 31;
  unsigned short row[32];
  for (int s = 0; s < 32; s++) {
    float a = 0.f;
    #pragma unroll
    for (int dd = 0; dd < 32; dd++) a += Gl[h * 1024 + s * 32 + dd] * wvt[dd * 32 + d];
    row[s] = f2b(a / zl[h * 32 + s]);
  }
  unsigned short* out = &KVB[(size_t)b * 65536 + (size_t)(h * 32 + d) * 256 + h * 32];
  #pragma unroll
  for (int e = 0; e < 4; e++) *(u16x8*)&out[e * 8] = *(u16x8*)&row[e * 8];
}

// Segment softmax in-place: rows of 256 = 8 segments of 32 (= 8 lanes x 4).
__global__ __launch_bounds__(256) void softmax_seg(unsigned short* __restrict__ Q) {
  const int lane = threadIdx.x & 63;
  const int wave = threadIdx.x >> 6;
  const size_t row = (size_t)blockIdx.x * 4 + wave;
  const size_t base = row * 256 + lane * 4;
  u16x4 uv = *(u16x4*)&Q[base];
  float x0 = b2f(uv[0]), x1 = b2f(uv[1]), x2 = b2f(uv[2]), x3 = b2f(uv[3]);
  float m = fmaxf(fmaxf(x0, x1), fmaxf(x2, x3));
  #pragma unroll
  for (int msk = 1; msk < 8; msk <<= 1) m = fmaxf(m, __shfl_xor(m, msk, 64));
  x0 = __expf(x0 - m); x1 = __expf(x1 - m); x2 = __expf(x2 - m); x3 = __expf(x3 - m);
  float ss = x0 + x1 + x2 + x3;
  #pragma unroll
  for (int msk = 1; msk < 8; msk <<= 1) ss += __shfl_xor(ss, msk, 64);
  const float rz = 1.0f / ss;
  u16x4 o;
  o[0] = f2b(x0 * rz); o[1] = f2b(x1 * rz); o[2] = f2b(x2 * rz); o[3] = f2b(x3 * rz);
  *(u16x4*)&Q[base] = o;
}

__global__ __launch_bounds__(256) void copy_h0(const unsigned short* __restrict__ src,
                                               unsigned short* __restrict__ dst) {
  size_t i = ((size_t)blockIdx.x * 256 + threadIdx.x) * 8;
  *(u16x8*)&dst[i] = *(const u16x8*)&src[i];
}

// ---------------------------------------------------------------------------
extern "C" void kernel_launch(void* const* d_in, const int* in_sizes, int n_in,
                              void* d_out, int out_size, void* d_ws, size_t ws_size,
                              hipStream_t stream)
{
  const void* fx   = d_in[0];
  const void* ln1w = d_in[1];
  const void* ln1b = d_in[2];
  const void* Wx   = d_in[3];
  const void* bx   = d_in[4];
  const void* Wq   = d_in[5];
  const void* Wk   = d_in[6];
  const void* Wv   = d_in[7];
  const void* Wo   = d_in[8];
  const void* bo   = d_in[9];
  const void* ln2w = d_in[10];
  const void* ln2b = d_in[11];
  const void* W1   = d_in[12];
  const void* b1   = d_in[13];
  const void* W2   = d_in[14];
  const void* b2   = d_in[15];

  // ws layout (24.7 MB)
  unsigned short* ws    = (unsigned short*)d_ws;
  unsigned short* hid   = ws;                      // 8,388,608 u16 (16 MB)
  float* Gp             = (float*)ws;              // overlay: 256*8448 f32 (8.7 MB)
  unsigned short* wtab  = ws + 8388608;            // 661,248 u16
  unsigned short* h0res = wtab + 661248;           // 2,097,152 u16 (4 MB)
  float* Gfin           = (float*)h0res;           // overlay: 67,584 f32 (270 KB)
  unsigned short* Wqbig = h0res + 2097152;         // 65,536
  unsigned short* Wkbig = Wqbig + 65536;           // 65,536
  unsigned short* KVB   = Wkbig + 65536;           // 524,288
  unsigned short* zbias = KVB + 524288;            // 256
  float* fpw = (float*)(zbias + 256);
  float* mu1 = fpw;
  float* rs1 = fpw + 65536;
  float* mu2 = fpw + 131072;
  float* rs2 = fpw + 196608;
  int* flagp = (int*)(fpw + 262144);

  const int OFF_LN1W=0, OFF_LN1B=256, OFF_WX=512, OFF_BX=66048,
            OFF_WQ=66304, OFF_WK=67328, OFF_WV=68352,
            OFF_WO=69376, OFF_BO=134912, OFF_LN2W=135168, OFF_LN2B=135424,
            OFF_W1=135680, OFF_B1=397824, OFF_W2=398848, OFF_B2=660992;

  unsigned short* xm  = (unsigned short*)d_out;    // lower half: xmid->qkv2d->h
  unsigned short* xup = xm + 16777216;             // upper half: E2d->QL->Qs

  // 0. dtype sniff + weight table
  sniff_kernel<<<1, 64, 0, stream>>>((const unsigned*)fx, flagp);
  CvtDesc cd;
  const void* srcs[15] = {ln1w, ln1b, Wx, bx, Wq, Wk, Wv, Wo, bo, ln2w, ln2b, W1, b1, W2, b2};
  const int offs[15]   = {OFF_LN1W, OFF_LN1B, OFF_WX, OFF_BX, OFF_WQ, OFF_WK, OFF_WV,
                          OFF_WO, OFF_BO, OFF_LN2W, OFF_LN2B, OFF_W1, OFF_B1, OFF_W2, OFF_B2};
  const int ns[15]     = {256, 256, 65536, 256, 1024, 1024, 1024, 65536, 256, 256, 256,
                          262144, 1024, 262144, 256};
  for (int i = 0; i < 15; i++) { cd.src[i] = srcs[i]; cd.off[i] = offs[i]; cd.n[i] = ns[i]; }
  cvt_tab<<<dim3(1024, 15), 256, 0, stream>>>(cd, wtab, flagp);
  build_big<<<256, 256, 0, stream>>>(wtab + OFF_WQ, wtab + OFF_WK, Wqbig, Wkbig);
  zero_u16<<<257, 256, 0, stream>>>(KVB, 524544);   // KVB + zbias

  // 1. LN1 stats; xmid = LN1(fx) @ Wx^T + bx -> d_out lower
  ln_stats<<<16384, 256, 0, stream>>>(fx, flagp, 1, mu1, rs1);
  gemm_bt_ln<<<dim3(512, 2), 256, 0, stream>>>(fx, flagp, 1, mu1, rs1,
      wtab + OFF_LN1W, wtab + OFF_LN1B, wtab + OFF_WX, wtab + OFF_BX,
      xm, 65536, 256, 256, 0);

  // 2. E2d = exp(xmid @ Wkbig^T) -> d_out upper
  gemm_bt<<<dim3(512, 2), 256, 0, stream>>>(xm, Wkbig, zbias, xup, 65536, 256, 256, 2, 0, 0);

  // 3. G partials + reduce; kv = (G@Wv^T)/z -> KVB block-diag
  accumG<<<256, 256, 0, stream>>>(xm, xup, Gp);
  reduceG<<<264, 256, 0, stream>>>(Gp, Gfin);
  kv_build<<<8, 256, 0, stream>>>(Gfin, wtab + OFF_WV, KVB);

  // 4. QL = xmid @ Wqbig^T -> upper (E2d dead); softmax in-place
  gemm_bt<<<dim3(512, 2), 256, 0, stream>>>(xm, Wqbig, zbias, xup, 65536, 256, 256, 0, 0, 0);
  softmax_seg<<<16384, 256, 0, stream>>>(xup);

  // 5. qkv2d = Qs @ KVB[b]^T -> lower (xmid dead), z-batched over b
  gemm_bt<<<dim3(64, 2, 8), 256, 0, stream>>>(xup, KVB, zbias, xm, 65536, 256, 256, 0,
                                              8192, 65536);

  // 6. h = qkv2d @ Wo^T + bo + fx, in-place over lower
  gemm_wo<<<512, 256, 0, stream>>>(xm, wtab + OFF_WO, wtab + OFF_BO, fx, flagp, xm);

  // 7. LN2 stats; protect chunk-0 residual (Gfin dead -> h0res reusable)
  ln_stats<<<16384, 256, 0, stream>>>(xm, flagp, 0, mu2, rs2);
  copy_h0<<<1024, 256, 0, stream>>>(xm, h0res);

  // 8. MLP, 8 chunks of 8192 rows, DESCENDING (fp32 out writes clobber only
  //    dead h rows; chunk 0 uses h0res). Gp dead -> hid usable.
  for (int c = 7; c >= 0; c--) {
    unsigned short* hrows = xm + (size_t)c * 8192 * 256;
    gemm_bt_ln<<<dim3(64, 8), 256, 0, stream>>>(hrows, flagp, 0,
        mu2 + c * 8192, rs2 + c * 8192, wtab + OFF_LN2W, wtab + OFF_LN2B,
        wtab + OFF_W1, wtab + OFF_B1, hid, 8192, 1024, 256, 1);
    gemm_w2out<<<dim3(64, 2), 256, 0, stream>>>(hid, wtab + OFF_W2, wtab + OFF_B2,
        (c == 0 ? h0res : hrows), d_out, flagp, (long)c * 8192);
  }
}

// Round 7
// 753.353 us; speedup vs baseline: 1.8996x; 1.1195x over previous
//
#include <hip/hip_runtime.h>
#include <math.h>

// ---------------------------------------------------------------------------
// LinearNO block, MI355X/gfx950. Inputs fp32 (sniffed; bf16 fallback).
// Interior bf16 MFMA. B=8 N=8192 C=256 H=8 D=32 S=32.
//
// R7 changes vs R6 (843 us):
//  * all MFMA GEMMs stage LDS via __builtin_amdgcn_global_load_lds width=16
//    (m97 pattern). LDS tiles UNPADDED stride-32 (DMA needs lane-contiguous
//    dest; tid*8 elem mapping = base + lane*16 bytes exactly).
//  * Wo GEMM no longer in-place: h -> xup (Qs dead), BN=128, grid 1024.
//    MLP runs ASCENDING; only chunk 7 self-races -> its h pre-copied to ws.
//  * W2out retiled BM=128 x BN=64 -> grid (64,4) = 256 blocks (was 128).
// ---------------------------------------------------------------------------

typedef __attribute__((ext_vector_type(8))) short bf8;
typedef __attribute__((ext_vector_type(4))) float f32x4;
typedef __attribute__((ext_vector_type(4))) unsigned short u16x4;
typedef __attribute__((ext_vector_type(8))) unsigned short u16x8;

__device__ __forceinline__ float b2f(unsigned short x) {
  union { unsigned u; float f; } t; t.u = ((unsigned)x) << 16; return t.f;
}
__device__ __forceinline__ unsigned short f2b(float f) {
  union { float f; unsigned u; } t; t.f = f;
  unsigned r = t.u + 0x7fffu + ((t.u >> 16) & 1u);
  return (unsigned short)(r >> 16);
}
__device__ __forceinline__ float gelu_exact(float x) {
  return 0.5f * x * (1.0f + erff(x * 0.7071067811865475f));
}

// async global->LDS, 16 B per lane. LDS dest must be base + lane*16.
typedef __attribute__((address_space(1))) const void gas_void;
typedef __attribute__((address_space(3))) void las_void;
__device__ __forceinline__ void gl_lds16(const void* g, void* l) {
  __builtin_amdgcn_global_load_lds((gas_void*)g, (las_void*)l, 16, 0, 0);
}

// --------------------------- dtype sniffer ---------------------------------
__global__ void sniff_kernel(const unsigned* __restrict__ fx, int* __restrict__ flag) {
  if (threadIdx.x == 0) {
    int cnt = 0;
    for (int i = 0; i < 64; i++) {
      unsigned e = (fx[i] >> 7) & 0xFFu;
      cnt += (e >= 117u && e <= 130u) ? 1 : 0;
    }
    *flag = (cnt >= 32) ? 1 : 0;   // 1 = bf16 inputs, 0 = fp32
  }
}

// --------------------------- weight table ----------------------------------
struct CvtDesc { const void* src[15]; int off[15]; int n[15]; };

__global__ __launch_bounds__(256) void cvt_tab(CvtDesc d, unsigned short* __restrict__ wtab,
                                               const int* __restrict__ flagp) {
  const int seg = blockIdx.y;
  const int i = blockIdx.x * 256 + threadIdx.x;
  if (i >= d.n[seg]) return;
  unsigned short o;
  if (*flagp) o = ((const unsigned short*)d.src[seg])[i];
  else        o = f2b(((const float*)d.src[seg])[i]);
  wtab[d.off[seg] + i] = o;
}

// Block-diagonal Wq_big / Wk_big [256,256]: big[h*32+s][h*32+d]=W[s][d].
__global__ __launch_bounds__(256) void build_big(
    const unsigned short* __restrict__ wq, const unsigned short* __restrict__ wk,
    unsigned short* __restrict__ Wqbig, unsigned short* __restrict__ Wkbig)
{
  const int idx = blockIdx.x * 256 + threadIdx.x;
  const int row = idx >> 8, col = idx & 255;
  const bool same = (row >> 5) == (col >> 5);
  const int wi = (row & 31) * 32 + (col & 31);
  Wqbig[idx] = same ? wq[wi] : (unsigned short)0;
  Wkbig[idx] = same ? wk[wi] : (unsigned short)0;
}

__global__ __launch_bounds__(256) void zero_u16(unsigned short* __restrict__ p, int n) {
  int i8 = (blockIdx.x * 256 + threadIdx.x) * 8;
  if (i8 < n) { u16x8 z = {}; *(u16x8*)&p[i8] = z; }
}

// --------------------------- LN stats --------------------------------------
__global__ __launch_bounds__(256) void ln_stats(
    const void* __restrict__ X, const int* __restrict__ flagp, int amode,
    float* __restrict__ MU, float* __restrict__ RS)
{
  const int lane = threadIdx.x & 63;
  const int wave = threadIdx.x >> 6;
  const size_t row = (size_t)blockIdx.x * 4 + wave;
  const size_t base = row * 256 + lane * 4;
  const bool abf = amode ? ((*flagp) != 0) : true;
  float x0, x1, x2, x3;
  if (abf) {
    u16x4 uv = *(const u16x4*)&((const unsigned short*)X)[base];
    x0 = b2f(uv[0]); x1 = b2f(uv[1]); x2 = b2f(uv[2]); x3 = b2f(uv[3]);
  } else {
    f32x4 t = *(const f32x4*)&((const float*)X)[base];
    x0 = t[0]; x1 = t[1]; x2 = t[2]; x3 = t[3];
  }
  float s = x0 + x1 + x2 + x3;
  float q = x0*x0 + x1*x1 + x2*x2 + x3*x3;
  #pragma unroll
  for (int m = 1; m < 64; m <<= 1) { s += __shfl_xor(s, m, 64); q += __shfl_xor(q, m, 64); }
  float mean = s * (1.0f / 256.0f);
  float var  = q * (1.0f / 256.0f) - mean * mean;
  if (lane == 0) { MU[row] = mean; RS[row] = rsqrtf(var + 1e-5f); }
}

// --------------------------- generic MFMA GEMM (DMA staging) ----------------
// Y[.,N] = A @ W^T + bias (+Res dtype-branched) ; act: 0 none, 2 exp.
// 128x128 tile, LDS stride 32 (unpadded, required by global_load_lds).
// z-batch: rows += z*mz, W += z*wz.
__global__ __launch_bounds__(256) void gemm_bt(
    const unsigned short* __restrict__ A,
    const unsigned short* __restrict__ W,
    const unsigned short* __restrict__ bias,
    const void* __restrict__ Res, const int* __restrict__ flagp,
    unsigned short* __restrict__ Y,
    int N, int K, int act, int mz, long wz)
{
  __shared__ __align__(16) unsigned short lA[128 * 32];   // 8 KB
  __shared__ __align__(16) unsigned short lB[128 * 32];   // 8 KB
  const int tid = threadIdx.x, lane = tid & 63, wave = tid >> 6;
  const size_t zrow = (size_t)blockIdx.z * mz;
  const int bm = blockIdx.x * 128, bn = blockIdx.y * 128;
  const int wm = (wave >> 1) * 64, wn = (wave & 1) * 64;
  const int quad = lane >> 4, l16 = lane & 15;
  const unsigned short* Wz = W + (size_t)blockIdx.z * wz;

  f32x4 acc[4][4] = {};
  const int r0 = tid >> 2;
  const int co = (tid & 3) * 8;
  const unsigned short* pa0 = &A[(zrow + bm + r0) * K + co];
  const unsigned short* pa1 = &A[(zrow + bm + r0 + 64) * K + co];
  const unsigned short* pb0 = &Wz[(size_t)(bn + r0) * K + co];
  const unsigned short* pb1 = &Wz[(size_t)(bn + r0 + 64) * K + co];
  unsigned short* la0 = &lA[tid * 8];
  unsigned short* la1 = &lA[2048 + tid * 8];
  unsigned short* lb0 = &lB[tid * 8];
  unsigned short* lb1 = &lB[2048 + tid * 8];

  for (int k0 = 0; k0 < K; k0 += 32) {
    __syncthreads();
    gl_lds16(pa0 + k0, la0);
    gl_lds16(pa1 + k0, la1);
    gl_lds16(pb0 + k0, lb0);
    gl_lds16(pb1 + k0, lb1);
    __syncthreads();

    bf8 af[4], bfr[4];
    #pragma unroll
    for (int i = 0; i < 4; i++) af[i]  = *(const bf8*)&lA[(wm + i * 16 + l16) * 32 + quad * 8];
    #pragma unroll
    for (int j = 0; j < 4; j++) bfr[j] = *(const bf8*)&lB[(wn + j * 16 + l16) * 32 + quad * 8];
    #pragma unroll
    for (int i = 0; i < 4; i++)
      #pragma unroll
      for (int j = 0; j < 4; j++)
        acc[i][j] = __builtin_amdgcn_mfma_f32_16x16x32_bf16(af[i], bfr[j], acc[i][j], 0, 0, 0);
  }

  const bool rbf = Res ? ((*flagp) != 0) : true;
  #pragma unroll
  for (int i = 0; i < 4; i++) {
    #pragma unroll
    for (int j = 0; j < 4; j++) {
      const int col  = bn + wn + j * 16 + l16;
      const int rowb = bm + wm + i * 16 + quad * 4;
      const float bv = b2f(bias[col]);
      #pragma unroll
      for (int r = 0; r < 4; r++) {
        float v = acc[i][j][r] + bv;
        if (act == 2) v = __expf(v);
        const size_t idx = (zrow + rowb + r) * N + col;
        if (Res)
          v += rbf ? b2f(((const unsigned short*)Res)[idx]) : ((const float*)Res)[idx];
        Y[idx] = f2b(v);
      }
    }
  }
}

// GEMM with LN applied to A during staging (amode: 1=flag dtype, 0=bf16);
// B side uses DMA staging. act=1 -> GELU.
__global__ __launch_bounds__(256) void gemm_bt_ln(
    const void* __restrict__ A, const int* __restrict__ flagp, int amode,
    const float* __restrict__ MU, const float* __restrict__ RS,
    const unsigned short* __restrict__ lw, const unsigned short* __restrict__ lb,
    const unsigned short* __restrict__ W, const unsigned short* __restrict__ bias,
    unsigned short* __restrict__ Y, int N, int K, int act)
{
  __shared__ __align__(16) unsigned short lA[128 * 32];
  __shared__ __align__(16) unsigned short lB[128 * 32];
  const int tid = threadIdx.x, lane = tid & 63, wave = tid >> 6;
  const int bm = blockIdx.x * 128, bn = blockIdx.y * 128;
  const int wm = (wave >> 1) * 64, wn = (wave & 1) * 64;
  const int quad = lane >> 4, l16 = lane & 15;
  const bool abf = amode ? ((*flagp) != 0) : true;
  const unsigned short* Ab = (const unsigned short*)A;
  const float* Af = (const float*)A;

  f32x4 acc[4][4] = {};
  const int r0 = tid >> 2;
  const int co = (tid & 3) * 8;
  const unsigned short* pb0 = &W[(size_t)(bn + r0) * K + co];
  const unsigned short* pb1 = &W[(size_t)(bn + r0 + 64) * K + co];

  for (int k0 = 0; k0 < K; k0 += 32) {
    u16x8 wv8 = *(const u16x8*)&lw[k0 + co];
    u16x8 bv8 = *(const u16x8*)&lb[k0 + co];
    __syncthreads();
    gl_lds16(pb0 + k0, &lB[tid * 8]);
    gl_lds16(pb1 + k0, &lB[2048 + tid * 8]);
    #pragma unroll
    for (int half = 0; half < 2; half++) {
      const int ar = bm + r0 + half * 64;
      const float m_ = MU[ar], r_ = RS[ar];
      float xv[8];
      if (abf) {
        u16x8 t = *(const u16x8*)&Ab[(size_t)ar * K + k0 + co];
        #pragma unroll
        for (int e = 0; e < 8; e++) xv[e] = b2f(t[e]);
      } else {
        f32x4 t0 = *(const f32x4*)&Af[(size_t)ar * K + k0 + co];
        f32x4 t1 = *(const f32x4*)&Af[(size_t)ar * K + k0 + co + 4];
        xv[0]=t0[0]; xv[1]=t0[1]; xv[2]=t0[2]; xv[3]=t0[3];
        xv[4]=t1[0]; xv[5]=t1[1]; xv[6]=t1[2]; xv[7]=t1[3];
      }
      u16x8 o;
      #pragma unroll
      for (int e = 0; e < 8; e++)
        o[e] = f2b((xv[e] - m_) * r_ * b2f(wv8[e]) + b2f(bv8[e]));
      *(u16x8*)&lA[half * 2048 + tid * 8] = o;
    }
    __syncthreads();

    bf8 af[4], bfr[4];
    #pragma unroll
    for (int i = 0; i < 4; i++) af[i]  = *(const bf8*)&lA[(wm + i * 16 + l16) * 32 + quad * 8];
    #pragma unroll
    for (int j = 0; j < 4; j++) bfr[j] = *(const bf8*)&lB[(wn + j * 16 + l16) * 32 + quad * 8];
    #pragma unroll
    for (int i = 0; i < 4; i++)
      #pragma unroll
      for (int j = 0; j < 4; j++)
        acc[i][j] = __builtin_amdgcn_mfma_f32_16x16x32_bf16(af[i], bfr[j], acc[i][j], 0, 0, 0);
  }

  #pragma unroll
  for (int i = 0; i < 4; i++) {
    #pragma unroll
    for (int j = 0; j < 4; j++) {
      const int col  = bn + wn + j * 16 + l16;
      const int rowb = bm + wm + i * 16 + quad * 4;
      const float bv = b2f(bias[col]);
      #pragma unroll
      for (int r = 0; r < 4; r++) {
        float v = acc[i][j][r] + bv;
        if (act) v = gelu_exact(v);
        Y[(size_t)(rowb + r) * N + col] = f2b(v);
      }
    }
  }
}

// W2 GEMM + residual + dtype-branched final store. BM=128 x BN=64 tile
// (grid 64x4 = 256 blocks). Waves 2x2, each 64x32 (acc 4x2).
__global__ __launch_bounds__(256) void gemm_w2out(
    const unsigned short* __restrict__ A,     // hid [8192,1024]
    const unsigned short* __restrict__ W,     // W2 [256,1024]
    const unsigned short* __restrict__ bias,
    const unsigned short* __restrict__ Res,   // h rows bf16
    void* __restrict__ OUT, const int* __restrict__ flagp, long out_row0)
{
  __shared__ __align__(16) unsigned short lA[128 * 32];   // 8 KB
  __shared__ __align__(16) unsigned short lB[64 * 32];    // 4 KB
  const int tid = threadIdx.x, lane = tid & 63, wave = tid >> 6;
  const int bm = blockIdx.x * 128, bn = blockIdx.y * 64;
  const int wm = (wave >> 1) * 64, wn = (wave & 1) * 32;
  const int quad = lane >> 4, l16 = lane & 15;
  const int K = 1024, N = 256;
  const bool obf = (*flagp) != 0;

  f32x4 acc[4][2] = {};
  const int r0 = tid >> 2;
  const int co = (tid & 3) * 8;
  const unsigned short* pa0 = &A[(size_t)(bm + r0) * K + co];
  const unsigned short* pa1 = &A[(size_t)(bm + r0 + 64) * K + co];
  const unsigned short* pb0 = &W[(size_t)(bn + r0) * K + co];

  for (int k0 = 0; k0 < 1024; k0 += 32) {
    __syncthreads();
    gl_lds16(pa0 + k0, &lA[tid * 8]);
    gl_lds16(pa1 + k0, &lA[2048 + tid * 8]);
    gl_lds16(pb0 + k0, &lB[tid * 8]);
    __syncthreads();

    bf8 af[4], bfr[2];
    #pragma unroll
    for (int i = 0; i < 4; i++) af[i]  = *(const bf8*)&lA[(wm + i * 16 + l16) * 32 + quad * 8];
    #pragma unroll
    for (int j = 0; j < 2; j++) bfr[j] = *(const bf8*)&lB[(wn + j * 16 + l16) * 32 + quad * 8];
    #pragma unroll
    for (int i = 0; i < 4; i++)
      #pragma unroll
      for (int j = 0; j < 2; j++)
        acc[i][j] = __builtin_amdgcn_mfma_f32_16x16x32_bf16(af[i], bfr[j], acc[i][j], 0, 0, 0);
  }

  #pragma unroll
  for (int i = 0; i < 4; i++) {
    #pragma unroll
    for (int j = 0; j < 2; j++) {
      const int col  = bn + wn + j * 16 + l16;
      const int rowb = bm + wm + i * 16 + quad * 4;
      const float bv = b2f(bias[col]);
      #pragma unroll
      for (int r = 0; r < 4; r++) {
        const int row = rowb + r;
        float v = acc[i][j][r] + bv + b2f(Res[(size_t)row * N + col]);
        const size_t oidx = (size_t)(out_row0 + row) * N + col;
        if (obf) ((unsigned short*)OUT)[oidx] = f2b(v);
        else     ((float*)OUT)[oidx] = v;
      }
    }
  }
}

// ---------------------------------------------------------------------------
// accumG: per 256-token block k: partial G[h,s,d] = sum_n E[n,h*32+s]*X[n,h*32+d]
// (+ z partial at [8192+tid]). Batch b owns blocks k = b*32 .. b*32+31.
// ---------------------------------------------------------------------------
__global__ __launch_bounds__(256) void accumG(
    const unsigned short* __restrict__ X,
    const unsigned short* __restrict__ E,
    float* __restrict__ Gp)                 // [256][8448]
{
  __shared__ float Xl[64 * 256];                         // 64 KB
  __shared__ __align__(16) unsigned short El[64 * 256];  // 32 KB
  const int tid = threadIdx.x;
  const int k = blockIdx.x;
  const int h = tid >> 5, s = tid & 31;

  float acc[32];
  #pragma unroll
  for (int d = 0; d < 32; d++) acc[d] = 0.f;
  float zacc = 0.f;

  for (int sub = 0; sub < 4; sub++) {
    const size_t r0s = (size_t)k * 256 + sub * 64;
    __syncthreads();
    #pragma unroll
    for (int i = 0; i < 8; i++) {
      const int flat = i * 2048 + tid * 8;
      u16x8 xv = *(const u16x8*)&X[r0s * 256 + flat];
      #pragma unroll
      for (int e = 0; e < 8; e++) Xl[flat + e] = b2f(xv[e]);
      *(u16x8*)&El[flat] = *(const u16x8*)&E[r0s * 256 + flat];
    }
    __syncthreads();

    for (int t = 0; t < 64; t++) {
      const float e = b2f(El[t * 256 + h * 32 + s]);
      zacc += e;
      const int xb = t * 256 + h * 32;
      #pragma unroll
      for (int dq = 0; dq < 8; dq++) {
        f32x4 xv = *(const f32x4*)&Xl[xb + dq * 4];
        acc[dq*4+0] += e * xv[0];
        acc[dq*4+1] += e * xv[1];
        acc[dq*4+2] += e * xv[2];
        acc[dq*4+3] += e * xv[3];
      }
    }
  }

  float* gp = &Gp[(size_t)k * 8448 + (size_t)tid * 32];
  #pragma unroll
  for (int dq = 0; dq < 8; dq++) {
    f32x4 o; o[0]=acc[dq*4]; o[1]=acc[dq*4+1]; o[2]=acc[dq*4+2]; o[3]=acc[dq*4+3];
    *(f32x4*)&gp[dq * 4] = o;
  }
  Gp[(size_t)k * 8448 + 8192 + tid] = zacc;
}

// Gfin[b][j] = sum_{i<32} Gp[b*32+i][j], b in 0..7.
__global__ __launch_bounds__(256) void reduceG(const float* __restrict__ Gp,
                                               float* __restrict__ Gfin) {
  const int o = blockIdx.x * 256 + threadIdx.x;
  if (o >= 67584) return;
  const int b = o / 8448;
  const int j = o - b * 8448;
  float s = 0.f;
  #pragma unroll 8
  for (int i = 0; i < 32; i++) s += Gp[(size_t)(b * 32 + i) * 8448 + j];
  Gfin[o] = s;
}

// kv_build (8 blocks): kv[b,h,s,d] = (sum_dd G*Wv[d,dd]) / z; block-diag KVB.
__global__ __launch_bounds__(256) void kv_build(
    const float* __restrict__ Gfin, const unsigned short* __restrict__ Wv,
    unsigned short* __restrict__ KVB)
{
  __shared__ float Gl[8192];
  __shared__ float zl[256];
  __shared__ float wvt[1024];
  const int tid = threadIdx.x;
  const int b = blockIdx.x;
  for (int i = tid; i < 8192; i += 256) Gl[i] = Gfin[(size_t)b * 8448 + i];
  zl[tid] = Gfin[(size_t)b * 8448 + 8192 + tid];
  for (int i = tid; i < 1024; i += 256) {
    const int dd = i >> 5, d = i & 31;
    wvt[i] = b2f(Wv[d * 32 + dd]);
  }
  __syncthreads();

  const int h = tid >> 5, d = tid & 31;
  unsigned short row[32];
  for (int s = 0; s < 32; s++) {
    float a = 0.f;
    #pragma unroll
    for (int dd = 0; dd < 32; dd++) a += Gl[h * 1024 + s * 32 + dd] * wvt[dd * 32 + d];
    row[s] = f2b(a / zl[h * 32 + s]);
  }
  unsigned short* out = &KVB[(size_t)b * 65536 + (size_t)(h * 32 + d) * 256 + h * 32];
  #pragma unroll
  for (int e = 0; e < 4; e++) *(u16x8*)&out[e * 8] = *(u16x8*)&row[e * 8];
}

// Segment softmax in-place: rows of 256 = 8 segments of 32 (8 lanes x 4).
__global__ __launch_bounds__(256) void softmax_seg(unsigned short* __restrict__ Q) {
  const int lane = threadIdx.x & 63;
  const int wave = threadIdx.x >> 6;
  const size_t row = (size_t)blockIdx.x * 4 + wave;
  const size_t base = row * 256 + lane * 4;
  u16x4 uv = *(u16x4*)&Q[base];
  float x0 = b2f(uv[0]), x1 = b2f(uv[1]), x2 = b2f(uv[2]), x3 = b2f(uv[3]);
  float m = fmaxf(fmaxf(x0, x1), fmaxf(x2, x3));
  #pragma unroll
  for (int msk = 1; msk < 8; msk <<= 1) m = fmaxf(m, __shfl_xor(m, msk, 64));
  x0 = __expf(x0 - m); x1 = __expf(x1 - m); x2 = __expf(x2 - m); x3 = __expf(x3 - m);
  float ss = x0 + x1 + x2 + x3;
  #pragma unroll
  for (int msk = 1; msk < 8; msk <<= 1) ss += __shfl_xor(ss, msk, 64);
  const float rz = 1.0f / ss;
  u16x4 o;
  o[0] = f2b(x0 * rz); o[1] = f2b(x1 * rz); o[2] = f2b(x2 * rz); o[3] = f2b(x3 * rz);
  *(u16x4*)&Q[base] = o;
}

__global__ __launch_bounds__(256) void copy_h0(const unsigned short* __restrict__ src,
                                               unsigned short* __restrict__ dst) {
  size_t i = ((size_t)blockIdx.x * 256 + threadIdx.x) * 8;
  *(u16x8*)&dst[i] = *(const u16x8*)&src[i];
}

// ---------------------------------------------------------------------------
extern "C" void kernel_launch(void* const* d_in, const int* in_sizes, int n_in,
                              void* d_out, int out_size, void* d_ws, size_t ws_size,
                              hipStream_t stream)
{
  const void* fx   = d_in[0];
  const void* ln1w = d_in[1];
  const void* ln1b = d_in[2];
  const void* Wx   = d_in[3];
  const void* bx   = d_in[4];
  const void* Wq   = d_in[5];
  const void* Wk   = d_in[6];
  const void* Wv   = d_in[7];
  const void* Wo   = d_in[8];
  const void* bo   = d_in[9];
  const void* ln2w = d_in[10];
  const void* ln2b = d_in[11];
  const void* W1   = d_in[12];
  const void* b1   = d_in[13];
  const void* W2   = d_in[14];
  const void* b2   = d_in[15];

  // ws layout (~24.7 MB)
  unsigned short* ws    = (unsigned short*)d_ws;
  unsigned short* hid   = ws;                      // 8,388,608 u16 (16 MB)
  float* Gp             = (float*)ws;              // overlay: 256*8448 f32
  unsigned short* wtab  = ws + 8388608;            // 661,248 u16
  unsigned short* h0res = wtab + 661248;           // 2,097,152 u16 (4 MB)
  float* Gfin           = (float*)h0res;           // overlay: 67,584 f32
  unsigned short* Wqbig = h0res + 2097152;         // 65,536
  unsigned short* Wkbig = Wqbig + 65536;           // 65,536
  unsigned short* KVB   = Wkbig + 65536;           // 524,288
  unsigned short* zbias = KVB + 524288;            // 256
  float* fpw = (float*)(zbias + 256);
  float* mu1 = fpw;
  float* rs1 = fpw + 65536;
  float* mu2 = fpw + 131072;
  float* rs2 = fpw + 196608;
  int* flagp = (int*)(fpw + 262144);

  const int OFF_LN1W=0, OFF_LN1B=256, OFF_WX=512, OFF_BX=66048,
            OFF_WQ=66304, OFF_WK=67328, OFF_WV=68352,
            OFF_WO=69376, OFF_BO=134912, OFF_LN2W=135168, OFF_LN2B=135424,
            OFF_W1=135680, OFF_B1=397824, OFF_W2=398848, OFF_B2=660992;

  unsigned short* xm  = (unsigned short*)d_out;    // lower: xmid->qkv2d (dead after Wo)
  unsigned short* xup = xm + 16777216;             // upper: E2d->QL->Qs->h

  // 0. dtype sniff + weight table
  sniff_kernel<<<1, 64, 0, stream>>>((const unsigned*)fx, flagp);
  CvtDesc cd;
  const void* srcs[15] = {ln1w, ln1b, Wx, bx, Wq, Wk, Wv, Wo, bo, ln2w, ln2b, W1, b1, W2, b2};
  const int offs[15]   = {OFF_LN1W, OFF_LN1B, OFF_WX, OFF_BX, OFF_WQ, OFF_WK, OFF_WV,
                          OFF_WO, OFF_BO, OFF_LN2W, OFF_LN2B, OFF_W1, OFF_B1, OFF_W2, OFF_B2};
  const int ns[15]     = {256, 256, 65536, 256, 1024, 1024, 1024, 65536, 256, 256, 256,
                          262144, 1024, 262144, 256};
  for (int i = 0; i < 15; i++) { cd.src[i] = srcs[i]; cd.off[i] = offs[i]; cd.n[i] = ns[i]; }
  cvt_tab<<<dim3(1024, 15), 256, 0, stream>>>(cd, wtab, flagp);
  build_big<<<256, 256, 0, stream>>>(wtab + OFF_WQ, wtab + OFF_WK, Wqbig, Wkbig);
  zero_u16<<<257, 256, 0, stream>>>(KVB, 524544);

  // 1. LN1 stats; xmid = LN1(fx) @ Wx^T + bx -> xm
  ln_stats<<<16384, 256, 0, stream>>>(fx, flagp, 1, mu1, rs1);
  gemm_bt_ln<<<dim3(512, 2), 256, 0, stream>>>(fx, flagp, 1, mu1, rs1,
      wtab + OFF_LN1W, wtab + OFF_LN1B, wtab + OFF_WX, wtab + OFF_BX,
      xm, 256, 256, 0);

  // 2. E2d = exp(xmid @ Wkbig^T) -> xup
  gemm_bt<<<dim3(512, 2), 256, 0, stream>>>(xm, Wkbig, zbias, nullptr, flagp,
                                            xup, 256, 256, 2, 0, 0);

  // 3. G partials + reduce; kv -> KVB block-diag
  accumG<<<256, 256, 0, stream>>>(xm, xup, Gp);
  reduceG<<<264, 256, 0, stream>>>(Gp, Gfin);
  kv_build<<<8, 256, 0, stream>>>(Gfin, wtab + OFF_WV, KVB);

  // 4. QL = xmid @ Wqbig^T -> xup (E2d dead); segment softmax in-place
  gemm_bt<<<dim3(512, 2), 256, 0, stream>>>(xm, Wqbig, zbias, nullptr, flagp,
                                            xup, 256, 256, 0, 0, 0);
  softmax_seg<<<16384, 256, 0, stream>>>(xup);

  // 5. qkv2d = Qs @ KVB[b]^T -> xm (xmid dead), z-batched over b
  gemm_bt<<<dim3(64, 2, 8), 256, 0, stream>>>(xup, KVB, zbias, nullptr, flagp,
                                              xm, 256, 256, 0, 8192, 65536);

  // 6. h = qkv2d @ Wo^T + bo + fx -> xup (Qs dead; NOT in-place -> full grid)
  gemm_bt<<<dim3(512, 2), 256, 0, stream>>>(xm, wtab + OFF_WO, wtab + OFF_BO, fx, flagp,
                                            xup, 256, 256, 0, 0, 0);

  // 7. LN2 stats on h; protect chunk-7 residual (out writes reach h7 last)
  ln_stats<<<16384, 256, 0, stream>>>(xup, flagp, 0, mu2, rs2);
  copy_h0<<<1024, 256, 0, stream>>>(xup + (size_t)7 * 2097152, h0res);

  // 8. MLP, 8 chunks of 8192 rows, ASCENDING. Out writes [0,8c) MB never touch
  //    h chunk c at [32+4c,36+4c) MB for c<8; only chunk 7's own W2out would
  //    race with its residual -> uses h0res copy. Gp dead -> hid usable.
  for (int c = 0; c < 8; c++) {
    unsigned short* hrows = xup + (size_t)c * 2097152;
    gemm_bt_ln<<<dim3(64, 8), 256, 0, stream>>>(hrows, flagp, 0,
        mu2 + c * 8192, rs2 + c * 8192, wtab + OFF_LN2W, wtab + OFF_LN2B,
        wtab + OFF_W1, wtab + OFF_B1, hid, 1024, 256, 1);
    gemm_w2out<<<dim3(64, 4), 256, 0, stream>>>(hid, wtab + OFF_W2, wtab + OFF_B2,
        (c == 7 ? h0res : hrows), d_out, flagp, (long)c * 8192);
  }
}